// Round 3
// baseline (57.641 us; speedup 1.0000x reference)
//
#include <hip/hip_runtime.h>

// AdjacencyMatchingLoss: B=8, NL=NQ=128, E=50000
// loss = -(1/B)*sum_b <M^T P_b , P_b A^T> / max(sum_w,1e-8)
// Identity: sum_{ij} M[ij](P A P^T)[ij] = sum_{jq}(M^T P)[jq]*(P A^T)[jq]
// Round-3 structure: NO global M, NO memset, 2 dispatches.
//   Each block (b, j-tile of 16) scans the edge list and scatter-adds its
//   own M column-slice into LDS (atomicAdd on shared). Block partials go to
//   distinct ws slots (plain stores -> poison-proof), final reduces 64+1.

constexpr int N = 128;
constexpr int BATCH = 8;
constexpr int JT = 16;        // j-columns per block
constexpr int APAD = 132;     // At row pad: 16B-aligned b128 reads, spread writes
constexpr int MPAD = 20;      // Msl row pad

__global__ __launch_bounds__(256) void uw_kernel(
    const float* __restrict__ P, const int* __restrict__ A,
    const int* __restrict__ pairs, const float* __restrict__ w,
    int E, float* __restrict__ ws)
{
    __shared__ float Pnat[N][N];     // 64 KB  : P_b natural
    __shared__ float At[N][APAD];    // 67.6 KB: At[p][q] = A[q][p]
    __shared__ float Msl[N][MPAD];   // 10 KB  : Msl[i][j'] = M[i][j0g+j']
    __shared__ float red[4];

    const int t = threadIdx.x;
    const int b = blockIdx.x >> 3;
    const int jt = blockIdx.x & 7;
    const int j0g = jt * JT;
    const float* __restrict__ Pb = P + b * N * N;

    // zero the M slice (LDS only)
    for (int idx = t; idx < N * MPAD; idx += 256)
        ((float*)Msl)[idx] = 0.f;

    // stage P_b (coalesced) and A^T (transpose in LDS)
    #pragma unroll
    for (int it = 0; it < 16; ++it) {
        int idx = t + 256 * it;
        ((float4*)Pnat)[idx] = ((const float4*)Pb)[idx];
    }
    #pragma unroll
    for (int it = 0; it < 16; ++it) {
        int idx = t + 256 * it;
        int4 av = ((const int4*)A)[idx];
        int row = idx >> 5;          // A row q
        int col = (idx & 31) << 2;   // A col p
        At[col + 0][row] = (av.x == 1) ? 1.f : 0.f;
        At[col + 1][row] = (av.y == 1) ? 1.f : 0.f;
        At[col + 2][row] = (av.z == 1) ? 1.f : 0.f;
        At[col + 3][row] = (av.w == 1) ? 1.f : 0.f;
    }
    __syncthreads();   // Msl zero (and staging) complete

    // edge scan: scatter this block's j-slice into LDS; block 0 sums all w
    float wsum = 0.f;
    #pragma unroll 4
    for (int e = t; e < E; e += 256) {
        int2 ij = ((const int2*)pairs)[e];
        float we = w[e];
        wsum += we;
        if ((ij.y >> 4) == jt)
            atomicAdd(&Msl[ij.x][ij.y & 15], we);
    }
    __syncthreads();   // Msl complete

    // fused U=M^T P_b, W=P_b A^T, partial = sum U.*W over this j-tile
    const int q0 = (t & 31) << 2;   // 4 q-columns per thread
    const int jl = (t >> 5) << 1;   // 2 local j-rows per thread

    float u0[4] = {0,0,0,0}, u1[4] = {0,0,0,0};
    float w0[4] = {0,0,0,0}, w1[4] = {0,0,0,0};
    #pragma unroll 4
    for (int k = 0; k < N; ++k) {
        float4 bu = *(const float4*)&Pnat[k][q0];
        float4 bw = *(const float4*)&At[k][q0];
        float a0 = Msl[k][jl];
        float a1 = Msl[k][jl + 1];
        float c0 = Pnat[j0g + jl][k];
        float c1 = Pnat[j0g + jl + 1][k];
        u0[0] += a0 * bu.x; u0[1] += a0 * bu.y; u0[2] += a0 * bu.z; u0[3] += a0 * bu.w;
        u1[0] += a1 * bu.x; u1[1] += a1 * bu.y; u1[2] += a1 * bu.z; u1[3] += a1 * bu.w;
        w0[0] += c0 * bw.x; w0[1] += c0 * bw.y; w0[2] += c0 * bw.z; w0[3] += c0 * bw.w;
        w1[0] += c1 * bw.x; w1[1] += c1 * bw.y; w1[2] += c1 * bw.z; w1[3] += c1 * bw.w;
    }

    float s = u0[0]*w0[0] + u0[1]*w0[1] + u0[2]*w0[2] + u0[3]*w0[3]
            + u1[0]*w1[0] + u1[1]*w1[1] + u1[2]*w1[2] + u1[3]*w1[3];
    #pragma unroll
    for (int off = 32; off > 0; off >>= 1)
        s += __shfl_down(s, off, 64);
    if ((t & 63) == 0) red[t >> 6] = s;
    __syncthreads();
    if (t == 0)
        ws[blockIdx.x] = red[0] + red[1] + red[2] + red[3];   // plain store

    // block 0 also reduces total weight (its scan saw every edge)
    if (blockIdx.x == 0) {
        __syncthreads();           // red[] free again
        #pragma unroll
        for (int off = 32; off > 0; off >>= 1)
            wsum += __shfl_down(wsum, off, 64);
        if ((t & 63) == 0) red[t >> 6] = wsum;
        __syncthreads();
        if (t == 0)
            ws[BATCH * 8] = red[0] + red[1] + red[2] + red[3];
    }
}

__global__ __launch_bounds__(64) void final_kernel(
    const float* __restrict__ ws, float* __restrict__ out)
{
    int t = threadIdx.x;
    float s = ws[t];               // 64 partials
    #pragma unroll
    for (int off = 32; off > 0; off >>= 1)
        s += __shfl_down(s, off, 64);
    if (t == 0) {
        float tw = fmaxf(ws[BATCH * 8], 1e-8f);
        out[0] = -(s / (float)BATCH) / tw;
    }
}

extern "C" void kernel_launch(void* const* d_in, const int* in_sizes, int n_in,
                              void* d_out, int out_size, void* d_ws, size_t ws_size,
                              hipStream_t stream)
{
    const float* P     = (const float*)d_in[0];
    const int*   d_hw  = (const int*)d_in[1];
    const int*   pairs = (const int*)d_in[2];
    const float* w     = (const float*)d_in[3];
    const int    E     = in_sizes[3];

    float* ws = (float*)d_ws;      // [0..63] block partials, [64] total weight

    uw_kernel<<<dim3(BATCH * 8), 256, 0, stream>>>(P, d_hw, pairs, w, E, ws);
    final_kernel<<<dim3(1), 64, 0, stream>>>(ws, (float*)d_out);
}